// Round 1
// baseline (160.429 us; speedup 1.0000x reference)
//
#include <hip/hip_runtime.h>

// out[n, lm, c] = node_feats[n,c] * sum_{e in seg(n)} edge_attrs[e,lm] * tp_weights[e, L[lm], c]
// L_OF_LM = [0, 1,1,1, 2,2,2,2,2, 3,3,3,3,3,3,3]
// One wave (64 lanes) per node; lane = channel. receiver_list is sorted ->
// binary search for segment bounds, accumulate in registers, no atomics.

__global__ __launch_bounds__(256) void imp_tp_kernel(
    const float* __restrict__ node_feats,   // [nnodes][64]
    const float* __restrict__ edge_attrs,   // [nedges][16]
    const float* __restrict__ tp_weights,   // [nedges][4][64]
    const int*   __restrict__ recv,         // [nedges] sorted
    int nnodes, int nedges,
    float* __restrict__ out)                // [nnodes][16][64]
{
    const int wave = (blockIdx.x * blockDim.x + threadIdx.x) >> 6;
    const int lane = threadIdx.x & 63;
    if (wave >= nnodes) return;
    const int n = wave;

    // lower_bound(recv, n) and lower_bound(recv, n+1); recv fits in L2 (1.6 MB)
    int lo = 0, hi = nedges;
    while (lo < hi) { int mid = (lo + hi) >> 1; if (recv[mid] < n) lo = mid + 1; else hi = mid; }
    const int start = lo;
    hi = nedges;
    while (lo < hi) { int mid = (lo + hi) >> 1; if (recv[mid] < n + 1) lo = mid + 1; else hi = mid; }
    const int end = lo;

    float acc[16];
    #pragma unroll
    for (int i = 0; i < 16; ++i) acc[i] = 0.f;

    for (int e = start; e < end; ++e) {
        // edge_attrs row: wave-uniform address, HW broadcast
        const float4* ea4 = reinterpret_cast<const float4*>(edge_attrs + (size_t)e * 16);
        const float4 ea0 = ea4[0];
        const float4 ea1 = ea4[1];
        const float4 ea2 = ea4[2];
        const float4 ea3 = ea4[3];
        // tp_weights: 4 coalesced dword loads (each 256B contiguous across wave)
        const float* w = tp_weights + (size_t)e * 256 + lane;
        const float w0 = w[0];
        const float w1 = w[64];
        const float w2 = w[128];
        const float w3 = w[192];

        acc[0]  += ea0.x * w0;
        acc[1]  += ea0.y * w1;
        acc[2]  += ea0.z * w1;
        acc[3]  += ea0.w * w1;
        acc[4]  += ea1.x * w2;
        acc[5]  += ea1.y * w2;
        acc[6]  += ea1.z * w2;
        acc[7]  += ea1.w * w2;
        acc[8]  += ea2.x * w2;
        acc[9]  += ea2.y * w3;
        acc[10] += ea2.z * w3;
        acc[11] += ea2.w * w3;
        acc[12] += ea3.x * w3;
        acc[13] += ea3.y * w3;
        acc[14] += ea3.z * w3;
        acc[15] += ea3.w * w3;
    }

    const float nf = node_feats[(size_t)n * 64 + lane];
    float* o = out + (size_t)n * 1024 + lane;
    #pragma unroll
    for (int lm = 0; lm < 16; ++lm) o[lm * 64] = acc[lm] * nf;
}

extern "C" void kernel_launch(void* const* d_in, const int* in_sizes, int n_in,
                              void* d_out, int out_size, void* d_ws, size_t ws_size,
                              hipStream_t stream) {
    const float* node_feats = (const float*)d_in[0];
    const float* edge_attrs = (const float*)d_in[1];
    const float* tp_weights = (const float*)d_in[2];
    const int*   recv       = (const int*)d_in[3];
    float* out = (float*)d_out;

    const int nnodes = in_sizes[0] / 64;   // node_feats flat = nnodes*64
    const int nedges = in_sizes[1] / 16;   // edge_attrs flat = nedges*16

    const int threads = 256;                       // 4 waves/block
    const int waves_needed = nnodes;
    const int blocks = (waves_needed * 64 + threads - 1) / threads;

    imp_tp_kernel<<<blocks, threads, 0, stream>>>(
        node_feats, edge_attrs, tp_weights, recv, nnodes, nedges, out);
}

// Round 2
// 123.820 us; speedup vs baseline: 1.2957x; 1.2957x over previous
//
#include <hip/hip_runtime.h>

// out[n, lm, c] = node_feats[n,c] * sum_{e in seg(n)} edge_attrs[e,lm] * tp_weights[e, L[lm], c]
// L_OF_LM = [0, 1,1,1, 2,2,2,2,2, 3,3,3,3,3,3,3]
//
// Round 1 -> 2 changes:
//  - segment bounds precomputed by a thread-per-node kernel into d_ws (removes
//    ~38 dependent L2 loads of serial binary-search latency per wave)
//  - 2-edge unrolled main loop, loads grouped before FMAs (deeper MLP)
//  - readfirstlane'd bounds so the edge index is provably uniform ->
//    edge_attrs rows load via scalar path (SGPRs), keeping VGPRs ~35

#define FMA16(EA_OFF, W0, W1, W2, W3)                                         \
    acc[0]  += ea[EA_OFF + 0]  * W0;                                          \
    acc[1]  += ea[EA_OFF + 1]  * W1;                                          \
    acc[2]  += ea[EA_OFF + 2]  * W1;                                          \
    acc[3]  += ea[EA_OFF + 3]  * W1;                                          \
    acc[4]  += ea[EA_OFF + 4]  * W2;                                          \
    acc[5]  += ea[EA_OFF + 5]  * W2;                                          \
    acc[6]  += ea[EA_OFF + 6]  * W2;                                          \
    acc[7]  += ea[EA_OFF + 7]  * W2;                                          \
    acc[8]  += ea[EA_OFF + 8]  * W2;                                          \
    acc[9]  += ea[EA_OFF + 9]  * W3;                                          \
    acc[10] += ea[EA_OFF + 10] * W3;                                          \
    acc[11] += ea[EA_OFF + 11] * W3;                                          \
    acc[12] += ea[EA_OFF + 12] * W3;                                          \
    acc[13] += ea[EA_OFF + 13] * W3;                                          \
    acc[14] += ea[EA_OFF + 14] * W3;                                          \
    acc[15] += ea[EA_OFF + 15] * W3;

__global__ __launch_bounds__(256) void bounds_kernel(
    const int* __restrict__ recv, int nedges, int nnodes,
    int* __restrict__ off)
{
    const int n = blockIdx.x * blockDim.x + threadIdx.x;
    if (n > nnodes) return;
    int lo = 0, hi = nedges;
    while (lo < hi) { int mid = (lo + hi) >> 1; if (recv[mid] < n) lo = mid + 1; else hi = mid; }
    off[n] = lo;
}

__global__ __launch_bounds__(256) void imp_tp_main(
    const float* __restrict__ node_feats,   // [nnodes][64]
    const float* __restrict__ edge_attrs,   // [nedges][16]
    const float* __restrict__ tp_weights,   // [nedges][4][64]
    const int*   __restrict__ off,          // [nnodes+1]
    int nnodes,
    float* __restrict__ out)                // [nnodes][16][64]
{
    const int wave = (blockIdx.x * blockDim.x + threadIdx.x) >> 6;
    const int lane = threadIdx.x & 63;
    if (wave >= nnodes) return;
    const int n = wave;

    const int start = __builtin_amdgcn_readfirstlane(off[n]);
    const int end   = __builtin_amdgcn_readfirstlane(off[n + 1]);

    const float nf = node_feats[(size_t)n * 64 + lane];

    float acc[16];
    #pragma unroll
    for (int i = 0; i < 16; ++i) acc[i] = 0.f;

    int e = start;
    for (; e + 2 <= end; e += 2) {
        // weights: 8 coalesced dword loads (256B/instr), issued together
        const float* wp = tp_weights + (size_t)e * 256 + lane;
        const float a0 = wp[0];
        const float a1 = wp[64];
        const float a2 = wp[128];
        const float a3 = wp[192];
        const float b0 = wp[256];
        const float b1 = wp[320];
        const float b2 = wp[384];
        const float b3 = wp[448];
        // edge_attrs: uniform address (e is SGPR) -> scalar loads
        const float* eap = edge_attrs + (size_t)e * 16;
        float ea[32];
        #pragma unroll
        for (int i = 0; i < 32; ++i) ea[i] = eap[i];

        FMA16(0,  a0, a1, a2, a3)
        FMA16(16, b0, b1, b2, b3)
    }
    if (e < end) {
        const float* wp = tp_weights + (size_t)e * 256 + lane;
        const float a0 = wp[0];
        const float a1 = wp[64];
        const float a2 = wp[128];
        const float a3 = wp[192];
        const float* eap = edge_attrs + (size_t)e * 16;
        float ea[16];
        #pragma unroll
        for (int i = 0; i < 16; ++i) ea[i] = eap[i];
        FMA16(0, a0, a1, a2, a3)
    }

    float* o = out + (size_t)n * 1024 + lane;
    #pragma unroll
    for (int lm = 0; lm < 16; ++lm) o[lm * 64] = acc[lm] * nf;
}

// Fallback (ws too small): in-wave binary search, known-correct from round 1.
__global__ __launch_bounds__(256) void imp_tp_fallback(
    const float* __restrict__ node_feats,
    const float* __restrict__ edge_attrs,
    const float* __restrict__ tp_weights,
    const int*   __restrict__ recv,
    int nnodes, int nedges,
    float* __restrict__ out)
{
    const int wave = (blockIdx.x * blockDim.x + threadIdx.x) >> 6;
    const int lane = threadIdx.x & 63;
    if (wave >= nnodes) return;
    const int n = wave;

    int lo = 0, hi = nedges;
    while (lo < hi) { int mid = (lo + hi) >> 1; if (recv[mid] < n) lo = mid + 1; else hi = mid; }
    const int start = lo;
    hi = nedges;
    while (lo < hi) { int mid = (lo + hi) >> 1; if (recv[mid] < n + 1) lo = mid + 1; else hi = mid; }
    const int end = lo;

    float acc[16];
    #pragma unroll
    for (int i = 0; i < 16; ++i) acc[i] = 0.f;

    for (int e = start; e < end; ++e) {
        const float4* ea4 = reinterpret_cast<const float4*>(edge_attrs + (size_t)e * 16);
        const float4 ea0 = ea4[0];
        const float4 ea1 = ea4[1];
        const float4 ea2 = ea4[2];
        const float4 ea3 = ea4[3];
        const float* w = tp_weights + (size_t)e * 256 + lane;
        const float w0 = w[0];
        const float w1 = w[64];
        const float w2 = w[128];
        const float w3 = w[192];

        acc[0]  += ea0.x * w0;
        acc[1]  += ea0.y * w1;
        acc[2]  += ea0.z * w1;
        acc[3]  += ea0.w * w1;
        acc[4]  += ea1.x * w2;
        acc[5]  += ea1.y * w2;
        acc[6]  += ea1.z * w2;
        acc[7]  += ea1.w * w2;
        acc[8]  += ea2.x * w2;
        acc[9]  += ea2.y * w3;
        acc[10] += ea2.z * w3;
        acc[11] += ea2.w * w3;
        acc[12] += ea3.x * w3;
        acc[13] += ea3.y * w3;
        acc[14] += ea3.z * w3;
        acc[15] += ea3.w * w3;
    }

    const float nf = node_feats[(size_t)n * 64 + lane];
    float* o = out + (size_t)n * 1024 + lane;
    #pragma unroll
    for (int lm = 0; lm < 16; ++lm) o[lm * 64] = acc[lm] * nf;
}

extern "C" void kernel_launch(void* const* d_in, const int* in_sizes, int n_in,
                              void* d_out, int out_size, void* d_ws, size_t ws_size,
                              hipStream_t stream) {
    const float* node_feats = (const float*)d_in[0];
    const float* edge_attrs = (const float*)d_in[1];
    const float* tp_weights = (const float*)d_in[2];
    const int*   recv       = (const int*)d_in[3];
    float* out = (float*)d_out;

    const int nnodes = in_sizes[0] / 64;
    const int nedges = in_sizes[1] / 16;

    const int threads = 256;  // 4 waves/block
    const int blocks = (nnodes * 64 + threads - 1) / threads;

    if (ws_size >= (size_t)(nnodes + 1) * sizeof(int)) {
        int* off = (int*)d_ws;
        const int bthreads = 256;
        const int bblocks = (nnodes + 1 + bthreads - 1) / bthreads;
        bounds_kernel<<<bblocks, bthreads, 0, stream>>>(recv, nedges, nnodes, off);
        imp_tp_main<<<blocks, threads, 0, stream>>>(
            node_feats, edge_attrs, tp_weights, off, nnodes, out);
    } else {
        imp_tp_fallback<<<blocks, threads, 0, stream>>>(
            node_feats, edge_attrs, tp_weights, recv, nnodes, nedges, out);
    }
}